// Round 4
// baseline (424.729 us; speedup 1.0000x reference)
//
#include <hip/hip_runtime.h>

// ---------------------------------------------------------------------------
// SHCA round 8:
//  - NEW gemm_p: 8-wave (512 thr) pipelined GEMM, wave tile 64x64,
//    BM x BN = 256x128 (or 128x256), BK=32, double-buffered 48KB LDS,
//    counted s_waitcnt vmcnt(3) + raw s_barrier (no vmcnt(0) drain in the
//    main loop), stage(t+2) issued after the compute barrier, setprio
//    around the MFMA cluster. Used for KV / expm / final GEMMs.
//  - epilogue staged in two 128x128 halves (fits 48KB); expm exp+rowsum
//    pass (round-7 vectorized form) runs inside the store pass.
//  - yq / attn stay on the proven gemm_mt (grids too small for big tiles).
// ---------------------------------------------------------------------------

#define FMAXF 3.402823466e38f

typedef __attribute__((ext_vector_type(8))) __bf16 bf16x8;
typedef __attribute__((ext_vector_type(4))) float f32x4;

static __device__ __forceinline__ short f2b(float f) {
  union { float f; unsigned u; } x; x.f = f;
  unsigned r = (x.u + 0x7FFFu + ((x.u >> 16) & 1u)) >> 16;
  return (short)r;
}
static __device__ __forceinline__ float b2f(short s) {
  union { unsigned u; float f; } x; x.u = ((unsigned)(unsigned short)s) << 16;
  return x.f;
}

static __device__ __forceinline__ void gl_lds16(const short* g, short* l) {
  __builtin_amdgcn_global_load_lds(
      (const __attribute__((address_space(1))) void*)g,
      (__attribute__((address_space(3))) void*)l, 16, 0, 0);
}

// ---------------- epilogue functors -----------------------------------------

struct EpiKV {
  static constexpr bool staged = true;
  static constexpr bool expm = false;
  static constexpr bool norm = false;
  short* xk; short* xv; const float* kb; const float* vb;
  __device__ float bias_at(int n) const { return n < 512 ? kb[n] : vb[n - 512]; }
  __device__ void store(int bz, int m, int n, int4 v) const {
    int b = m & 7; long x = m >> 3;
    if (n < 512) *(int4*)(xk + ((long)b * 2048 + x) * 512 + n) = v;
    else         *(int4*)(xv + ((long)b * 2048 + x) * 512 + (n - 512)) = v;
  }
};

struct EpiYq {
  static constexpr bool staged = true;
  static constexpr bool expm = false;
  static constexpr bool norm = false;
  short* out; const float* bias;
  __device__ float bias_at(int n) const { return bias[n]; }
  __device__ void store(int bz, int m, int n, int4 v) const {
    *(int4*)(out + (((long)(m & 7)) * 1024 + (m >> 3)) * 512 + n) = v;
  }
};

struct EpiLogitExp {  // E = exp(scale*logit + g*align), 0 if masked; + rowsums
  static constexpr bool staged = true;
  static constexpr bool expm = true;
  static constexpr bool norm = false;
  short* out;           // E [8][1024][2048] bf16
  const float* align;   // [8][1024][2048] f32
  const int* mask;      // [8][1024][2048] int
  const float* alw;     // gate param
  float* rowsum;        // [8][1024] f32 (pre-zeroed)
  __device__ float bias_at(int n) const { return 0.0f; }
  __device__ void store(int bz, int m, int n, int4 v) const {
    *(int4*)(out + ((long)bz * 1024 + m) * 2048 + n) = v;
  }
};

struct EpiConcatNorm {  // attn@xv output, scaled by 1/rowsum per row
  static constexpr bool staged = true;
  static constexpr bool expm = false;
  static constexpr bool norm = true;
  short* out; const float* rowsum;
  __device__ float bias_at(int n) const { return 0.0f; }
  __device__ void store(int bz, int m, int n, int4 v) const {
    *(int4*)(out + ((long)m * 8 + bz) * 1536 + 1024 + n) = v;
  }
};

struct EpiOut {  // fp32 output, direct stores
  static constexpr bool staged = false;
  static constexpr bool expm = false;
  static constexpr bool norm = false;
  float* out; const float* bias;
  __device__ void direct(int bz, int m, int n, float v) const {
    out[(long)m * 1024 + n] = v + bias[n];
  }
};

// ---------------- pipelined BM x BN GEMM (A x B^T), BK=32, 8 waves ----------
// 512 threads, wave tile 64x64 (4x2 or 2x4 wave grid). Double-buffered LDS,
// counted vmcnt(3), raw barriers, stage(t+2) after the compute barrier.
// Requires: Mtiles (M/BM) divisible by 8, grid.x = Mtiles*Ntiles, tlog =
// log2(Ntiles).
template <int BM, int BN, typename Epi>
__global__ __launch_bounds__(512, 2) void gemm_p(
    const short* __restrict__ A, long sAb, int lda,
    const short* __restrict__ B, long sBb, int ldb,
    int K, int tlog, Epi epi) {
  constexpr int RT = BM + BN;          // 384 staged rows, 64B each (BK=32)
  constexpr int TS = RT * 32;          // shorts per K-tile buffer (12288)
  __shared__ short S[2 * TS];          // 49152 B

  const int tid = threadIdx.x;
  const int lane = tid & 63, wave = tid >> 6;
  const int quad = lane >> 4, l16 = lane & 15;
  const int bz = blockIdx.z;

  const int id = blockIdx.x;
  const int xcd = id & 7;
  const int rr = id >> 3;
  const int n0 = (rr & ((1 << tlog) - 1)) * BN;
  const int m0 = (((rr >> tlog) << 3) + xcd) * BM;

  // staging: 3 x 16B slots/thread; row = slot>>2, granule (slot&3) XOR-swz
  const short* gp[3];
#pragma unroll
  for (int u = 0; u < 3; u++) {
    int slot = u * 512 + tid;
    int row = slot >> 2;
    int g = (slot & 3) ^ ((row ^ (row >> 2)) & 3);
    gp[u] = (row < BM
                 ? A + (long)bz * sAb + (long)(m0 + row) * lda
                 : B + (long)bz * sBb + (long)(n0 + row - BM) * ldb) + g * 8;
  }

  const int wm = (BM == 256) ? (wave >> 1) * 64 : (wave >> 2) * 64;
  const int wn = (BM == 256) ? (wave & 1) * 64 : (wave & 3) * 64;

  // fragment LDS offsets (shorts), swizzle-matched to staging
  int aoff[4], boff[4];
#pragma unroll
  for (int i = 0; i < 4; i++) {
    int ra = wm + i * 16 + l16;
    aoff[i] = ra * 32 + ((quad ^ ((ra ^ (ra >> 2)) & 3)) * 8);
    int rb = BM + wn + i * 16 + l16;
    boff[i] = rb * 32 + ((quad ^ ((rb ^ (rb >> 2)) & 3)) * 8);
  }

  f32x4 acc[4][4] = {};
  const int nt = K >> 5;

  // prologue: tiles 0 and 1 in flight
#pragma unroll
  for (int u = 0; u < 3; u++)
    gl_lds16(gp[u], S + (u * 512 + tid) * 8);
#pragma unroll
  for (int u = 0; u < 3; u++)
    gl_lds16(gp[u] + 32, S + TS + (u * 512 + tid) * 8);

  for (int t = 0; t < nt; t++) {
    const short* Sb = S + (t & 1) * TS;
    if (t + 1 < nt) asm volatile("s_waitcnt vmcnt(3)" ::: "memory");
    else            asm volatile("s_waitcnt vmcnt(0)" ::: "memory");
    __builtin_amdgcn_s_barrier();
    asm volatile("" ::: "memory");

    union { int4 v; bf16x8 f; } a[4], b[4];
#pragma unroll
    for (int i = 0; i < 4; i++) a[i].v = *(const int4*)(Sb + aoff[i]);
#pragma unroll
    for (int j = 0; j < 4; j++) b[j].v = *(const int4*)(Sb + boff[j]);
    __builtin_amdgcn_s_setprio(1);
#pragma unroll
    for (int i = 0; i < 4; i++)
#pragma unroll
      for (int j = 0; j < 4; j++)
        acc[i][j] = __builtin_amdgcn_mfma_f32_16x16x32_bf16(a[i].f, b[j].f,
                                                            acc[i][j], 0, 0, 0);
    __builtin_amdgcn_s_setprio(0);

    asm volatile("s_waitcnt lgkmcnt(0)" ::: "memory");
    __builtin_amdgcn_s_barrier();
    asm volatile("" ::: "memory");
    if (t + 2 < nt) {
      short* Sw = S + (t & 1) * TS;
      const int ko = (t + 2) * 32;
#pragma unroll
      for (int u = 0; u < 3; u++)
        gl_lds16(gp[u] + ko, Sw + (u * 512 + tid) * 8);
    }
  }

  // ---- epilogue: staged 128x128 halves (32KB), or direct fp32 ----
  if constexpr (Epi::staged) {
    constexpr bool splitM = (BM == 256);
#pragma unroll
    for (int h = 0; h < 2; h++) {
      __syncthreads();
      if constexpr (splitM) {
        if ((wm >> 7) == h) {
          const int lr = wm & 127;
#pragma unroll
          for (int j = 0; j < 4; j++) {
            const int c = wn + j * 16 + l16;
            const float bj = epi.bias_at(n0 + c);
#pragma unroll
            for (int i = 0; i < 4; i++)
#pragma unroll
              for (int r = 0; r < 4; r++)
                S[(lr + i * 16 + quad * 4 + r) * 128 + c] =
                    f2b(acc[i][j][r] + bj);
          }
        }
      } else {
        if ((wn >> 7) == h) {
          const int lc = wn & 127;
#pragma unroll
          for (int j = 0; j < 4; j++) {
            const int cl = lc + j * 16 + l16;
            const float bj = epi.bias_at(n0 + h * 128 + cl);
#pragma unroll
            for (int i = 0; i < 4; i++)
#pragma unroll
              for (int r = 0; r < 4; r++)
                S[(wm + i * 16 + quad * 4 + r) * 128 + cl] =
                    f2b(acc[i][j][r] + bj);
          }
        }
      }
      __syncthreads();
      const int gm0 = splitM ? m0 + h * 128 : m0;
      const int gn0 = splitM ? n0 : n0 + h * 128;
      if constexpr (Epi::expm) {
        const float g = 1.0f / (1.0f + __expf(-epi.alw[0]));
        const float scale = 0.04419417382415922f;  // 1/sqrt(512)
#pragma unroll
        for (int it = 0; it < 4; it++) {
          const int c = it * 512 + tid;
          const int row = c >> 4, colc = (c & 15) * 8;
          const long gy = (long)bz * 1024 + gm0 + row;
          const float* ap = epi.align + gy * 2048 + gn0 + colc;
          const int*   mp = epi.mask + gy * 2048 + gn0 + colc;
          float4 a0 = *(const float4*)ap;
          float4 a1 = *(const float4*)(ap + 4);
          int4 q0 = *(const int4*)mp;
          int4 q1 = *(const int4*)(mp + 4);
          union { short s[8]; int4 v; } d;
          d.v = *(const int4*)(S + row * 128 + colc);
          float e[8];
          e[0] = q0.x ? 0.0f : __expf(fmaf(b2f(d.s[0]), scale, g * a0.x));
          e[1] = q0.y ? 0.0f : __expf(fmaf(b2f(d.s[1]), scale, g * a0.y));
          e[2] = q0.z ? 0.0f : __expf(fmaf(b2f(d.s[2]), scale, g * a0.z));
          e[3] = q0.w ? 0.0f : __expf(fmaf(b2f(d.s[3]), scale, g * a0.w));
          e[4] = q1.x ? 0.0f : __expf(fmaf(b2f(d.s[4]), scale, g * a1.x));
          e[5] = q1.y ? 0.0f : __expf(fmaf(b2f(d.s[5]), scale, g * a1.y));
          e[6] = q1.z ? 0.0f : __expf(fmaf(b2f(d.s[6]), scale, g * a1.z));
          e[7] = q1.w ? 0.0f : __expf(fmaf(b2f(d.s[7]), scale, g * a1.w));
          float part = 0.0f;
#pragma unroll
          for (int k = 0; k < 8; k++) { part += e[k]; d.s[k] = f2b(e[k]); }
          epi.store(bz, gm0 + row, gn0 + colc, d.v);
          part += __shfl_xor(part, 1);
          part += __shfl_xor(part, 2);
          part += __shfl_xor(part, 4);
          part += __shfl_xor(part, 8);
          if ((tid & 15) == 0) atomicAdd(epi.rowsum + gy, part);
        }
      } else {
#pragma unroll
        for (int it = 0; it < 4; it++) {
          const int c = it * 512 + tid;
          const int row = c >> 4, colc = (c & 15) * 8;
          int4 v = *(const int4*)(S + row * 128 + colc);
          epi.store(bz, gm0 + row, gn0 + colc, v);
        }
      }
    }
  } else {
#pragma unroll
    for (int i = 0; i < 4; i++)
#pragma unroll
      for (int j = 0; j < 4; j++)
#pragma unroll
        for (int r = 0; r < 4; r++)
          epi.direct(bz, m0 + wm + i * 16 + quad * 4 + r,
                     n0 + wn + j * 16 + l16, acc[i][j][r]);
  }
}

// ---------------- TM x 128 bf16 MFMA GEMM (A x B^T), BK=64 ------------------
// retained for yq (TM=64) and attn (TM=64) whose grids are too small for the
// big-tile kernel.
template <int TM, typename Epi>
__global__ __launch_bounds__(256) void gemm_mt(
    const short* __restrict__ A, long sAb, int lda,
    const short* __restrict__ B, long sBb, int ldb,
    int K, int tlog, Epi epi) {
  constexpr int R = TM + 128;
  constexpr int SEGS = R / 32;
  constexpr int LDSN = (R * 64 > TM * 128) ? R * 64 : TM * 128;
  __shared__ short S[LDSN];

  const int tid = threadIdx.x;
  const int lane = tid & 63, wave = tid >> 6;
  const int bz = blockIdx.z;

  const int id = blockIdx.x;
  const int xcd = id & 7;
  const int rr = id >> 3;
  const int n0 = (rr & ((1 << tlog) - 1)) * 128;
  const int m0 = (((rr >> tlog) << 3) + xcd) * TM;

  const short* gp[SEGS];
#pragma unroll
  for (int t = 0; t < SEGS; t++) {
    int slot = t * 256 + tid;
    int row = slot >> 3;
    int gcol = ((slot & 7) ^ (row & 7)) * 8;
    gp[t] = (row < TM)
                ? A + (long)bz * sAb + (long)(m0 + row) * lda + gcol
                : B + (long)bz * sBb + (long)(n0 + row - TM) * ldb + gcol;
  }

  const int wm = (TM == 128) ? (wave & 1) * 64 : 0;
  const int wn = (TM == 128) ? (wave >> 1) * 64 : wave * 32;
  constexpr int MI = 4;
  constexpr int MJ = (TM == 128) ? 4 : 2;
  const int quad = lane >> 4, l16 = lane & 15;
  const int xr = l16 & 7;

  f32x4 acc[MI][MJ] = {};

  for (int k0 = 0; k0 < K; k0 += 64) {
#pragma unroll
    for (int t = 0; t < SEGS; t++)
      gl_lds16(gp[t] + k0, S + (t * 256 + tid) * 8);
    __syncthreads();

#pragma unroll
    for (int kk = 0; kk < 2; kk++) {
      union { int4 v; bf16x8 f; } a[MI], b[MJ];
      const int g = ((kk << 2) + quad);
#pragma unroll
      for (int i = 0; i < MI; i++)
        a[i].v = *(const int4*)(S + (wm + i * 16 + l16) * 64 + (g ^ xr) * 8);
#pragma unroll
      for (int j = 0; j < MJ; j++)
        b[j].v = *(const int4*)(S + (TM + wn + j * 16 + l16) * 64 + (g ^ xr) * 8);
#pragma unroll
      for (int i = 0; i < MI; i++)
#pragma unroll
        for (int j = 0; j < MJ; j++)
          acc[i][j] = __builtin_amdgcn_mfma_f32_16x16x32_bf16(a[i].f, b[j].f,
                                                              acc[i][j], 0, 0, 0);
    }
    __syncthreads();
  }

  if constexpr (Epi::staged) {
    if constexpr (Epi::norm) {
#pragma unroll
      for (int i = 0; i < MI; i++)
#pragma unroll
        for (int r = 0; r < 4; r++) {
          const int row = wm + i * 16 + quad * 4 + r;
          const float inv = 1.0f / epi.rowsum[(long)bz * 1024 + m0 + row];
#pragma unroll
          for (int j = 0; j < MJ; j++)
            S[row * 128 + wn + j * 16 + l16] = f2b(acc[i][j][r] * inv);
        }
    } else {
#pragma unroll
      for (int j = 0; j < MJ; j++) {
        const int c = wn + j * 16 + l16;
        const float bj = epi.bias_at(n0 + c);
#pragma unroll
        for (int i = 0; i < MI; i++)
#pragma unroll
          for (int r = 0; r < 4; r++)
            S[(wm + i * 16 + quad * 4 + r) * 128 + c] = f2b(acc[i][j][r] + bj);
      }
    }
    __syncthreads();
#pragma unroll
    for (int t = 0; t < TM / 16; t++) {
      int c = t * 256 + tid;
      int row = c >> 4, colc = (c & 15) * 8;
      int4 v = *(const int4*)(S + row * 128 + colc);
      epi.store(bz, m0 + row, n0 + colc, v);
    }
  } else {
#pragma unroll
    for (int i = 0; i < MI; i++)
#pragma unroll
      for (int j = 0; j < MJ; j++)
#pragma unroll
        for (int r = 0; r < 4; r++)
          epi.direct(bz, m0 + wm + i * 16 + quad * 4 + r,
                     n0 + wn + j * 16 + l16, acc[i][j][r]);
  }
}

// ---------------- converts --------------------------------------------------
__global__ __launch_bounds__(256) void cvt_f32_bf16(const float* __restrict__ in,
                                                    short* __restrict__ out,
                                                    long n4) {
  long i = (long)blockIdx.x * 256 + threadIdx.x;
  if (i >= n4) return;
  float4 f = ((const float4*)in)[i];
  union { short s[4]; long long v; } o;
  o.s[0] = f2b(f.x); o.s[1] = f2b(f.y); o.s[2] = f2b(f.z); o.s[3] = f2b(f.w);
  ((long long*)out)[i] = o.v;
}

// all 4 weight matrices in one dispatch; also zeroes the rowsum accumulator.
__global__ __launch_bounds__(256) void cvt_weights(
    const float* __restrict__ xk_w, const float* __restrict__ xv_w,
    const float* __restrict__ yq_w, const float* __restrict__ yw_w,
    short* __restrict__ wkv, short* __restrict__ wyq, short* __restrict__ wyw,
    float* __restrict__ rowsum) {
  long i = (long)blockIdx.x * 256 + threadIdx.x;
  if (i < 8192) rowsum[i] = 0.0f;
  const float* src; long long* dst; long off;
  if (i < 131072)      { src = xk_w; dst = (long long*)wkv; off = i; }
  else if (i < 262144) { src = xv_w; dst = (long long*)wkv + 131072; off = i - 131072; }
  else if (i < 393216) { src = yq_w; dst = (long long*)wyq; off = i - 262144; }
  else                 { src = yw_w; dst = (long long*)wyw; off = i - 393216; }
  float4 f = ((const float4*)src)[off];
  union { short s[4]; long long v; } o;
  o.s[0] = f2b(f.x); o.s[1] = f2b(f.y); o.s[2] = f2b(f.z); o.s[3] = f2b(f.w);
  dst[off] = o.v;
}

__global__ __launch_bounds__(256) void cvt_y_concat(const float* __restrict__ in,
                                                    short* __restrict__ out) {
  long idx = (long)blockIdx.x * 256 + threadIdx.x;
  long row = idx >> 8;
  int c = (int)(idx & 255) << 2;
  float4 f = *(const float4*)(in + row * 1024 + c);
  union { short s[4]; unsigned long long v; } o;
  o.s[0] = f2b(f.x); o.s[1] = f2b(f.y); o.s[2] = f2b(f.z); o.s[3] = f2b(f.w);
  *(unsigned long long*)(out + row * 1536 + c) = o.v;
}

// ---------------- xv[b][x][h] -> xvt[b][h][x] (32x32 LDS tiles) -------------
__global__ __launch_bounds__(256) void transpose_xv(const short* __restrict__ xv,
                                                    short* __restrict__ xvt) {
  __shared__ short t[32][36];
  const int b = blockIdx.z;
  const long x0 = (long)blockIdx.x * 32, h0 = (long)blockIdx.y * 32;
  const int r = threadIdx.x >> 3, c = (threadIdx.x & 7) * 4;
  const short* src = xv + ((long)b * 2048 + x0 + r) * 512 + h0 + c;
  *(int2*)&t[r][c] = *(const int2*)src;
  __syncthreads();
  union { short s[4]; int2 v; } o;
  o.s[0] = t[c + 0][r]; o.s[1] = t[c + 1][r];
  o.s[2] = t[c + 2][r]; o.s[3] = t[c + 3][r];
  short* dst = xvt + ((long)b * 512 + h0 + r) * 2048 + x0 + c;
  *(int2*)dst = o.v;
}

// ---------------------------------------------------------------------------

extern "C" void kernel_launch(void* const* d_in, const int* in_sizes, int n_in,
                              void* d_out, int out_size, void* d_ws, size_t ws_size,
                              hipStream_t stream) {
  const float* X    = (const float*)d_in[0];
  const float* Y    = (const float*)d_in[1];
  const float* alig = (const float*)d_in[2];
  const int*   mask = (const int*)d_in[3];
  const float* Xk_w = (const float*)d_in[4];
  const float* Xk_b = (const float*)d_in[5];
  const float* Xv_w = (const float*)d_in[6];
  const float* Xv_b = (const float*)d_in[7];
  const float* Yq_w = (const float*)d_in[8];
  const float* Yq_b = (const float*)d_in[9];
  const float* Yw_w = (const float*)d_in[10];
  const float* Yw_b = (const float*)d_in[11];
  const float* alw  = (const float*)d_in[12];
  float* out = (float*)d_out;

  char* ws = (char*)d_ws;
  short* xbf    = (short*)(ws + 0);          // 33.5MB X bf16; reused as E
  short* E      = (short*)(ws + 0);          // [8][1024][2048] bf16 (after KV)
  short* xk     = (short*)(ws + 33554432);   // 16.8MB [8][2048][512]
  short* xv     = (short*)(ws + 50331648);   // 16.8MB [8][2048][512]
  short* xvt    = (short*)(ws + 67108864);   // 16.8MB [8][512][2048]
  short* yq     = (short*)(ws + 83886080);   //  8.4MB [8][1024][512]
  short* concat = (short*)(ws + 92274688);   // 25.2MB [8192][1536]
  short* wkv    = (short*)(ws + 117440512);  //  2.1MB [1024][1024] (Xk|Xv)
  short* wyq    = (short*)(ws + 119537664);  //  1.0MB [512][1024]
  short* wyw    = (short*)(ws + 120586240);  //  3.1MB [1024][1536]
  float* rowsum = (float*)(ws + 123731968);  //  32KB [8][1024] f32

  // --- converts (3 dispatches; cvt_weights also zeroes rowsum) ---
  cvt_f32_bf16<<<16384, 256, 0, stream>>>(X, xbf, 4194304);
  cvt_y_concat<<<8192, 256, 0, stream>>>(Y, concat);
  cvt_weights<<<3072, 256, 0, stream>>>(Xk_w, Xv_w, Yq_w, Yw_w, wkv, wyq, wyw,
                                        rowsum);

  // --- fused xk/xv projection: (16384 x 1024) x (1024 x 1024)^T ---
  // BM=256: Mtiles=64, Ntiles=8 (tlog=3), grid 512
  gemm_p<256, 128, EpiKV><<<dim3(512, 1, 1), 512, 0, stream>>>(
      xbf, 0, 1024, wkv, 0, 1024, 1024, 3, EpiKV{xk, xv, Xk_b, Xv_b});

  // --- yq: concat[:, :1024] (8192 x 1024, ld 1536) x (512 x 1024)^T ---
  gemm_mt<64, EpiYq><<<dim3(512, 1, 1), 256, 0, stream>>>(
      concat, 0, 1536, wyq, 0, 1024, 1024, 2, EpiYq{yq, Yq_b});

  // --- xv -> xvt ---
  transpose_xv<<<dim3(64, 16, 8), 256, 0, stream>>>(xv, xvt);

  // --- E = exp(softmax numerator): yq (1024x512) x xk^T (2048x512), fused
  //     scale + gated align + mask + exp + rowsum atomics (vectorized) ---
  // BM=128, BN=256: Mtiles=8, Ntiles=8 (tlog=3), grid 64 per batch
  gemm_p<128, 256, EpiLogitExp><<<dim3(64, 1, 8), 512, 0, stream>>>(
      yq, (long)1024 * 512, 512, xk, (long)2048 * 512, 512, 512, 3,
      EpiLogitExp{E, alig, mask, alw, rowsum});

  // --- attn_feat = (E @ xvt^T) / rowsum -> concat[:, 1024:] ---
  gemm_mt<64, EpiConcatNorm><<<dim3(64, 1, 8), 256, 0, stream>>>(
      E, (long)1024 * 2048, 2048, xvt, (long)512 * 2048, 2048, 2048, 2,
      EpiConcatNorm{concat, rowsum});

  // --- final: (8192x1536) x (1024x1536)^T -> fp32 out ---
  // BM=256: Mtiles=32, Ntiles=8 (tlog=3), grid 256
  gemm_p<256, 128, EpiOut><<<dim3(256, 1, 1), 512, 0, stream>>>(
      concat, 0, 1536, wyw, 0, 1536, 1536, 3, EpiOut{out, Yw_b});
}

// Round 5
// 415.747 us; speedup vs baseline: 1.0216x; 1.0216x over previous
//
#include <hip/hip_runtime.h>

// ---------------------------------------------------------------------------
// SHCA round 9 (on top of round-7 423.3us config; gemm_p reverted — proven
// neutral, matches learn_hip m99/m100/m131-140):
//  1. batch<->XCD affinity (BXCD) for expm + attn GEMMs: bz = id&7 so each
//     XCD's L2 holds exactly its batch's xk/yq (3MB) or E/xvt slices.
//  2. transpose_xv folded into KV epilogue: C tile staged with granule-XOR
//     ((row>>3)&7) so the n>=512 half is read TRANSPOSED from LDS and
//     written straight to xvt (xv buffer + transpose kernel deleted,
//     -33.6MB HBM).
//  3. single fused convert kernel (X, Y->concat, 4 weights, rowsum zero).
// ---------------------------------------------------------------------------

#define FMAXF 3.402823466e38f

typedef __attribute__((ext_vector_type(8))) __bf16 bf16x8;
typedef __attribute__((ext_vector_type(4))) float f32x4;

static __device__ __forceinline__ short f2b(float f) {
  union { float f; unsigned u; } x; x.f = f;
  unsigned r = (x.u + 0x7FFFu + ((x.u >> 16) & 1u)) >> 16;
  return (short)r;
}
static __device__ __forceinline__ float b2f(short s) {
  union { unsigned u; float f; } x; x.u = ((unsigned)(unsigned short)s) << 16;
  return x.f;
}

static __device__ __forceinline__ void gl_lds16(const short* g, short* l) {
  __builtin_amdgcn_global_load_lds(
      (const __attribute__((address_space(1))) void*)g,
      (__attribute__((address_space(3))) void*)l, 16, 0, 0);
}

// ---------------- epilogue functors -----------------------------------------

struct EpiKV {  // n<512 -> xk rows; n>=512 -> TRANSPOSED to xvt (in-LDS)
  static constexpr bool staged = true;
  static constexpr bool expm = false;
  static constexpr bool norm = false;
  static constexpr bool kvt = true;
  short* xk; short* xvt; const float* kb; const float* vb;
  __device__ float bias_at(int n) const { return n < 512 ? kb[n] : vb[n - 512]; }
  __device__ void store(int bz, int m, int n, int4 v) const {
    *(int4*)(xk + (((long)(m & 7)) * 2048 + (m >> 3)) * 512 + n) = v;
  }
};

struct EpiYq {
  static constexpr bool staged = true;
  static constexpr bool expm = false;
  static constexpr bool norm = false;
  static constexpr bool kvt = false;
  short* out; const float* bias;
  __device__ float bias_at(int n) const { return bias[n]; }
  __device__ void store(int bz, int m, int n, int4 v) const {
    *(int4*)(out + (((long)(m & 7)) * 1024 + (m >> 3)) * 512 + n) = v;
  }
};

struct EpiLogitExp {  // E = exp(scale*logit + g*align), 0 if masked; + rowsums
  static constexpr bool staged = true;
  static constexpr bool expm = true;
  static constexpr bool norm = false;
  static constexpr bool kvt = false;
  short* out;           // E [8][1024][2048] bf16
  const float* align;   // [8][1024][2048] f32
  const int* mask;      // [8][1024][2048] int
  const float* alw;     // gate param
  float* rowsum;        // [8][1024] f32 (pre-zeroed)
  __device__ float bias_at(int n) const { return 0.0f; }
  __device__ void store(int bz, int m, int n, int4 v) const {
    *(int4*)(out + ((long)bz * 1024 + m) * 2048 + n) = v;
  }
};

struct EpiConcatNorm {  // attn@xv output, scaled by 1/rowsum per row
  static constexpr bool staged = true;
  static constexpr bool expm = false;
  static constexpr bool norm = true;
  static constexpr bool kvt = false;
  short* out; const float* rowsum;
  __device__ float bias_at(int n) const { return 0.0f; }
  __device__ void store(int bz, int m, int n, int4 v) const {
    *(int4*)(out + ((long)m * 8 + bz) * 1536 + 1024 + n) = v;
  }
};

struct EpiOut {  // fp32 output, direct stores
  static constexpr bool staged = false;
  static constexpr bool expm = false;
  static constexpr bool norm = false;
  static constexpr bool kvt = false;
  float* out; const float* bias;
  __device__ void direct(int bz, int m, int n, float v) const {
    out[(long)m * 1024 + n] = v + bias[n];
  }
};

// ---------------- TM x 128 bf16 MFMA GEMM (A x B^T), BK=64 ------------------
// 256 threads. TM=128: 4 waves 2x2 (wave 64x64, 16 mfma/k-step).
//              TM=64 : 4 waves 1x4 (wave 64x32,  8 mfma/k-step).
// BXCD: bz = id&7 (batch pinned to one XCD for L2 locality); otherwise the
// m-tile carries the XCD swizzle and bz = blockIdx.z.
// Epilogue C-stage uses granule-XOR ((row>>3)&7) so both row-major int4
// reads and (kvt) stride-8-row transposed reads are bank-spread.
template <int TM, typename Epi, bool BXCD = false>
__global__ __launch_bounds__(256) void gemm_mt(
    const short* __restrict__ A, long sAb, int lda,
    const short* __restrict__ B, long sBb, int ldb,
    int K, int tlog, Epi epi) {
  constexpr int R = TM + 128;           // staged rows (A then B), 128B each
  constexpr int SEGS = R / 32;          // 16B slots per thread
  constexpr int LDSN = (R * 64 > TM * 128) ? R * 64 : TM * 128;
  __shared__ short S[LDSN];

  const int tid = threadIdx.x;
  const int lane = tid & 63, wave = tid >> 6;

  const int id = blockIdx.x;
  int bz, n0, m0;
  if constexpr (BXCD) {
    bz = id & 7;
    const int rr = id >> 3;
    n0 = (rr & ((1 << tlog) - 1)) * 128;
    m0 = (rr >> tlog) * TM;
  } else {
    bz = blockIdx.z;
    const int xcd = id & 7;
    const int rr = id >> 3;
    n0 = (rr & ((1 << tlog) - 1)) * 128;
    m0 = (((rr >> tlog) << 3) + xcd) * TM;
  }

  // staging pointers: slot = t*256 + tid; row = slot>>3, granule = slot&7
  const short* gp[SEGS];
#pragma unroll
  for (int t = 0; t < SEGS; t++) {
    int slot = t * 256 + tid;
    int row = slot >> 3;
    int gcol = ((slot & 7) ^ (row & 7)) * 8;
    gp[t] = (row < TM)
                ? A + (long)bz * sAb + (long)(m0 + row) * lda + gcol
                : B + (long)bz * sBb + (long)(n0 + row - TM) * ldb + gcol;
  }

  const int wm = (TM == 128) ? (wave & 1) * 64 : 0;
  const int wn = (TM == 128) ? (wave >> 1) * 64 : wave * 32;
  constexpr int MI = 4;
  constexpr int MJ = (TM == 128) ? 4 : 2;
  const int quad = lane >> 4, l16 = lane & 15;
  const int xr = l16 & 7;               // row-XOR for fragment reads

  f32x4 acc[MI][MJ] = {};

  for (int k0 = 0; k0 < K; k0 += 64) {
#pragma unroll
    for (int t = 0; t < SEGS; t++)
      gl_lds16(gp[t] + k0, S + (t * 256 + tid) * 8);
    __syncthreads();

#pragma unroll
    for (int kk = 0; kk < 2; kk++) {
      union { int4 v; bf16x8 f; } a[MI], b[MJ];
      const int g = ((kk << 2) + quad);
#pragma unroll
      for (int i = 0; i < MI; i++)
        a[i].v = *(const int4*)(S + (wm + i * 16 + l16) * 64 + (g ^ xr) * 8);
#pragma unroll
      for (int j = 0; j < MJ; j++)
        b[j].v = *(const int4*)(S + (TM + wn + j * 16 + l16) * 64 + (g ^ xr) * 8);
#pragma unroll
      for (int i = 0; i < MI; i++)
#pragma unroll
        for (int j = 0; j < MJ; j++)
          acc[i][j] = __builtin_amdgcn_mfma_f32_16x16x32_bf16(a[i].f, b[j].f,
                                                              acc[i][j], 0, 0, 0);
    }
    __syncthreads();
  }

  if constexpr (Epi::staged) {
    // C-stage address: granule XOR by (row>>3)&7 (bijective within row)
    auto sco = [](int row, int col) {
      return row * 128 + ((((col >> 3) ^ ((row >> 3) & 7)) << 3) | (col & 7));
    };
    if constexpr (Epi::norm) {
#pragma unroll
      for (int i = 0; i < MI; i++)
#pragma unroll
        for (int r = 0; r < 4; r++) {
          const int row = wm + i * 16 + quad * 4 + r;
          const float inv = 1.0f / epi.rowsum[(long)bz * 1024 + m0 + row];
#pragma unroll
          for (int j = 0; j < MJ; j++)
            S[sco(row, wn + j * 16 + l16)] = f2b(acc[i][j][r] * inv);
        }
    } else {
#pragma unroll
      for (int j = 0; j < MJ; j++) {
        const int c = wn + j * 16 + l16;
        const float bj = epi.bias_at(n0 + c);
#pragma unroll
        for (int i = 0; i < MI; i++)
#pragma unroll
          for (int r = 0; r < 4; r++)
            S[sco(wm + i * 16 + quad * 4 + r, c)] = f2b(acc[i][j][r] + bj);
      }
    }
    __syncthreads();

    if constexpr (Epi::expm) {
      // ---- fused softmax-numerator pass: vectorized, branch-free ----
      const float g = 1.0f / (1.0f + __expf(-epi.alw[0]));
      const float scale = 0.04419417382415922f;  // 1/sqrt(512)
#pragma unroll
      for (int t = 0; t < TM / 16; t++) {
        const int c = t * 256 + tid;
        const int row = c >> 4, colc = (c & 15) * 8;
        const long gy = (long)bz * 1024 + m0 + row;
        const float* ap = epi.align + gy * 2048 + n0 + colc;
        const int*   mp = epi.mask + gy * 2048 + n0 + colc;
        float4 a0 = *(const float4*)ap;
        float4 a1 = *(const float4*)(ap + 4);
        int4 q0 = *(const int4*)mp;
        int4 q1 = *(const int4*)(mp + 4);
        union { short s[8]; int4 v; } d;
        d.v = *(const int4*)(S + row * 128 + (((c & 15) ^ ((row >> 3) & 7)) << 3));
        float e[8];
        e[0] = q0.x ? 0.0f : __expf(fmaf(b2f(d.s[0]), scale, g * a0.x));
        e[1] = q0.y ? 0.0f : __expf(fmaf(b2f(d.s[1]), scale, g * a0.y));
        e[2] = q0.z ? 0.0f : __expf(fmaf(b2f(d.s[2]), scale, g * a0.z));
        e[3] = q0.w ? 0.0f : __expf(fmaf(b2f(d.s[3]), scale, g * a0.w));
        e[4] = q1.x ? 0.0f : __expf(fmaf(b2f(d.s[4]), scale, g * a1.x));
        e[5] = q1.y ? 0.0f : __expf(fmaf(b2f(d.s[5]), scale, g * a1.y));
        e[6] = q1.z ? 0.0f : __expf(fmaf(b2f(d.s[6]), scale, g * a1.z));
        e[7] = q1.w ? 0.0f : __expf(fmaf(b2f(d.s[7]), scale, g * a1.w));
        float part = 0.0f;
#pragma unroll
        for (int k = 0; k < 8; k++) { part += e[k]; d.s[k] = f2b(e[k]); }
        epi.store(bz, m0 + row, n0 + colc, d.v);
        part += __shfl_xor(part, 1);
        part += __shfl_xor(part, 2);
        part += __shfl_xor(part, 4);
        part += __shfl_xor(part, 8);
        if ((tid & 15) == 0) atomicAdd(epi.rowsum + gy, part);
      }
    } else if constexpr (Epi::kvt) {
      if (n0 < 512) {
        // xk half: normal coalesced int4 stores
#pragma unroll
        for (int t = 0; t < TM / 16; t++) {
          int c = t * 256 + tid;
          int row = c >> 4, cg = c & 15;
          int4 v = *(const int4*)(S + row * 128 + ((cg ^ ((row >> 3) & 7)) << 3));
          epi.store(bz, m0 + row, n0 + cg * 8, v);
        }
      } else {
        // xv half: transposed read from LDS -> xvt[b][h][x] (16 x per chunk)
        const int x0 = m0 >> 3;
#pragma unroll
        for (int it = 0; it < 4; it++) {
          int c = it * 256 + tid;
          int hl = c & 127, b = (c >> 7) & 7;
          union { short s[16]; int4 v[2]; } o;
#pragma unroll
          for (int x = 0; x < 16; x++) {
            int row = x * 8 + b;  // (row>>3)&7 == x&7
            o.s[x] = S[row * 128 + (((hl >> 3) ^ (x & 7)) << 3) + (hl & 7)];
          }
          short* dst = epi.xvt + ((long)b * 512 + (n0 - 512) + hl) * 2048 + x0;
          *(int4*)dst = o.v[0];
          *(int4*)(dst + 8) = o.v[1];
        }
      }
    } else {
#pragma unroll
      for (int t = 0; t < TM / 16; t++) {
        int c = t * 256 + tid;
        int row = c >> 4, cg = c & 15;
        int4 v = *(const int4*)(S + row * 128 + ((cg ^ ((row >> 3) & 7)) << 3));
        epi.store(bz, m0 + row, n0 + cg * 8, v);
      }
    }
  } else {
#pragma unroll
    for (int i = 0; i < MI; i++)
#pragma unroll
      for (int j = 0; j < MJ; j++)
#pragma unroll
        for (int r = 0; r < 4; r++)
          epi.direct(bz, m0 + wm + i * 16 + quad * 4 + r,
                     n0 + wn + j * 16 + l16, acc[i][j][r]);
  }
}

// ---------------- fused converts (one dispatch) ------------------------------
// ranges (float4 units): X 4194304 | Y 2097152 | weights 786432 = 7077888
__global__ __launch_bounds__(256) void cvt_all(
    const float* __restrict__ X, const float* __restrict__ Y,
    const float* __restrict__ xk_w, const float* __restrict__ xv_w,
    const float* __restrict__ yq_w, const float* __restrict__ yw_w,
    short* __restrict__ xbf, short* __restrict__ concat,
    short* __restrict__ wkv, short* __restrict__ wyq, short* __restrict__ wyw,
    float* __restrict__ rowsum) {
  long i = (long)blockIdx.x * 256 + threadIdx.x;
  if (i < 8192) rowsum[i] = 0.0f;
  float4 f;
  long long* dst;
  if (i < 4194304) {
    f = ((const float4*)X)[i];
    dst = (long long*)xbf + i;
  } else if (i < 6291456) {
    long idx = i - 4194304;
    long row = idx >> 8;
    int c = (int)(idx & 255) << 2;
    f = *(const float4*)(Y + row * 1024 + c);
    dst = (long long*)(concat + row * 1536 + c);
  } else {
    long j = i - 6291456;
    const float* src; long off;
    if (j < 131072)      { src = xk_w; dst = (long long*)wkv + j; off = j; }
    else if (j < 262144) { src = xv_w; dst = (long long*)wkv + j; off = j - 131072; }
    else if (j < 393216) { src = yq_w; dst = (long long*)wyq + (j - 262144); off = j - 262144; }
    else                 { src = yw_w; dst = (long long*)wyw + (j - 393216); off = j - 393216; }
    f = ((const float4*)src)[off];
  }
  union { short s[4]; long long v; } o;
  o.s[0] = f2b(f.x); o.s[1] = f2b(f.y); o.s[2] = f2b(f.z); o.s[3] = f2b(f.w);
  *dst = o.v;
}

// ---------------------------------------------------------------------------

extern "C" void kernel_launch(void* const* d_in, const int* in_sizes, int n_in,
                              void* d_out, int out_size, void* d_ws, size_t ws_size,
                              hipStream_t stream) {
  const float* X    = (const float*)d_in[0];
  const float* Y    = (const float*)d_in[1];
  const float* alig = (const float*)d_in[2];
  const int*   mask = (const int*)d_in[3];
  const float* Xk_w = (const float*)d_in[4];
  const float* Xk_b = (const float*)d_in[5];
  const float* Xv_w = (const float*)d_in[6];
  const float* Xv_b = (const float*)d_in[7];
  const float* Yq_w = (const float*)d_in[8];
  const float* Yq_b = (const float*)d_in[9];
  const float* Yw_w = (const float*)d_in[10];
  const float* Yw_b = (const float*)d_in[11];
  const float* alw  = (const float*)d_in[12];
  float* out = (float*)d_out;

  char* ws = (char*)d_ws;
  short* xbf    = (short*)(ws + 0);          // 33.5MB X bf16; reused as E
  short* E      = (short*)(ws + 0);          // [8][1024][2048] bf16 (after KV)
  short* xk     = (short*)(ws + 33554432);   // 16.8MB [8][2048][512]
  short* xvt    = (short*)(ws + 67108864);   // 16.8MB [8][512][2048]
  short* yq     = (short*)(ws + 83886080);   //  8.4MB [8][1024][512]
  short* concat = (short*)(ws + 92274688);   // 25.2MB [8192][1536]
  short* wkv    = (short*)(ws + 117440512);  //  2.1MB [1024][1024] (Xk|Xv)
  short* wyq    = (short*)(ws + 119537664);  //  1.0MB [512][1024]
  short* wyw    = (short*)(ws + 120586240);  //  3.1MB [1024][1536]
  float* rowsum = (float*)(ws + 123731968);  //  32KB [8][1024] f32

  // --- all converts in one dispatch (also zeroes rowsum) ---
  cvt_all<<<27648, 256, 0, stream>>>(X, Y, Xk_w, Xv_w, Yq_w, Yw_w,
                                     xbf, concat, wkv, wyq, wyw, rowsum);

  // --- fused xk/xv projection: (16384 x 1024) x (1024 x 1024)^T ---
  //     n<512 -> xk; n>=512 -> transposed in-epilogue to xvt
  gemm_mt<128, EpiKV><<<dim3(1024, 1, 1), 256, 0, stream>>>(
      xbf, 0, 1024, wkv, 0, 1024, 1024, 3, EpiKV{xk, xvt, Xk_b, Xv_b});

  // --- yq: concat[:, :1024] (8192 x 1024, ld 1536) x (512 x 1024)^T ---
  gemm_mt<64, EpiYq><<<dim3(512, 1, 1), 256, 0, stream>>>(
      concat, 0, 1536, wyq, 0, 1024, 1024, 2, EpiYq{yq, Yq_b});

  // --- E = exp(softmax numerator): yq (1024x512) x xk^T (2048x512) ---
  //     batch = XCD (id&7): per-XCD L2 holds its batch's xk+yq (3MB)
  gemm_mt<128, EpiLogitExp, true><<<dim3(1024, 1, 1), 256, 0, stream>>>(
      yq, (long)1024 * 512, 512, xk, (long)2048 * 512, 512, 512, 4,
      EpiLogitExp{E, alig, mask, alw, rowsum});

  // --- attn_feat = (E @ xvt^T) / rowsum -> concat[:, 1024:] (batch=XCD) ---
  gemm_mt<64, EpiConcatNorm, true><<<dim3(512, 1, 1), 256, 0, stream>>>(
      E, (long)1024 * 2048, 2048, xvt, (long)512 * 2048, 2048, 2048, 2,
      EpiConcatNorm{concat, rowsum});

  // --- final: (8192x1536) x (1024x1536)^T -> fp32 out ---
  gemm_mt<128, EpiOut><<<dim3(512, 1, 1), 256, 0, stream>>>(
      concat, 0, 1536, wyw, 0, 1536, 1536, 3, EpiOut{out, Yw_b});
}